// Round 2
// baseline (1031.283 us; speedup 1.0000x reference)
//
#include <hip/hip_runtime.h>
#include <stdint.h>

// ---------------------------------------------------------------------------
// Exact top-k (k=10%) magnitude mask via 16-bit-prefix radix select.
//
// Layout:
//  d_out (128 MiB, 33554432 fp32 words) is scratch until final masks land:
//    words [0, 131072)        : two 65536-bin uint32 histograms (m=0, m=1)
//                               (clobbered later by matrix-0's provisional mask)
//    words [RBASE, 33554432)  : candidate (idx,u) pairs, 65536 cap per matrix
//                               (matrix-1 provisional write SKIPS this tail;
//                                select_fix_k also never writes there;
//                                fill_tail_k writes it exactly at the end)
//  d_ws: 16 uint32 control words. per matrix m at ws+8*m:
//    [0]=P (16-bit prefix of threshold), [1]=rank within prefix bin,
//    [2]=candidate count, [3]=T (exact 31-bit threshold), [4]=C (tie cutoff idx)
// ---------------------------------------------------------------------------

#define NBINS       65536u
#define HWORDS      (2u * NBINS)                    // 131072 words of d_out
#define CCAP        65536u                          // expected ~32768/matrix -> 2x headroom
#define TOTAL_WORDS 33554432u                       // d_out words (2 x 16.7M fp32)
#define RWORDS      (2u * CCAP * 2u)                // 262144 words = 1 MiB
#define RBASE       (TOTAL_WORDS - RWORDS)          // 33292288
#define SKIP_WORD   (RBASE - 16777216u)             // 16515072 (local fp32 idx, matrix 1)
#define SKIP_F4     (SKIP_WORD / 4u)                // 4128768 (float4 idx in matrix 1)

__global__ void init_k(uint32_t* __restrict__ ws, uint32_t* __restrict__ outbuf) {
  uint32_t i = blockIdx.x * blockDim.x + threadIdx.x;
  if (i < HWORDS) outbuf[i] = 0u;
  if (i < 16u) ws[i] = 0u;
}

// PASS 1: full scan, 65536-bin histogram of bits 30..15.
// Bins packed 2x16-bit in 128 KiB LDS; per-block max bin count ~256 so no
// 16-bit overflow. Hottest bin ~0.2% of elements -> near-zero LDS atomic
// serialization (vs 12.5% with a 2048-bin histogram).
__global__ __launch_bounds__(1024, 1) void hist_k(const float* __restrict__ A,
                                                  const float* __restrict__ B,
                                                  uint32_t* __restrict__ outbuf,
                                                  int nvec) {
  const int m = blockIdx.y;
  const float4* __restrict__ src = (const float4*)(m == 0 ? A : B);
  uint32_t* gh = outbuf + (uint32_t)m * NBINS;
  __shared__ uint32_t h[NBINS / 2];
  for (int i = threadIdx.x; i < (int)(NBINS / 2); i += blockDim.x) h[i] = 0u;
  __syncthreads();
  int idx0 = blockIdx.x * blockDim.x + threadIdx.x;
  int stride = gridDim.x * blockDim.x;
  for (int i = idx0; i < nvec; i += stride) {
    float4 f = src[i];
    const float v[4] = {f.x, f.y, f.z, f.w};
#pragma unroll
    for (int c = 0; c < 4; c++) {
      uint32_t u = __float_as_uint(v[c]) & 0x7fffffffu;
      uint32_t b = u >> 15;
      atomicAdd(&h[b >> 1], 1u << ((b & 1u) * 16u));
    }
  }
  __syncthreads();
  // merge: skip zero words (sparse tail of low binades)
  for (int w = threadIdx.x; w < (int)(NBINS / 2); w += blockDim.x) {
    uint32_t x = h[w];
    uint32_t c0 = x & 0xffffu, c1 = x >> 16;
    if (c0) atomicAdd(&gh[2 * w], c0);
    if (c1) atomicAdd(&gh[2 * w + 1], c1);
  }
}

// Scan the 65536-bin histogram: find bin containing rank j -> P, rank-in-bin.
__global__ __launch_bounds__(1024, 1) void scan16_k(const uint32_t* __restrict__ outbuf,
                                                    uint32_t* __restrict__ ws, uint32_t j) {
  const int m = blockIdx.x;
  const uint32_t* gh = outbuf + (uint32_t)m * NBINS;
  uint32_t* W = ws + m * 8;
  __shared__ uint32_t ps[1024];
  const int t = threadIdx.x;
  uint32_t s = 0u;
  for (int k = 0; k < 64; k++) s += gh[t * 64 + k];
  ps[t] = s;
  __syncthreads();
  for (int off = 1; off < 1024; off <<= 1) {
    uint32_t v = (t >= off) ? ps[t - off] : 0u;
    __syncthreads();
    ps[t] += v;
    __syncthreads();
  }
  uint32_t base = (t == 0) ? 0u : ps[t - 1];
  for (int k = 0; k < 64; k++) {
    uint32_t b = (uint32_t)t * 64u + (uint32_t)k;
    uint32_t c = gh[b];
    if (j >= base && j < base + c) { W[0] = b; W[1] = j - base; }  // one match
    base += c;
  }
}

// PASS 2 (fused with final mask): write provisional mask by 16-bit prefix
// comparison; collect the ~32K prefix-matching (idx,u) pairs into the tail of
// d_out. Matrix-1 blocks skip writing the tail region (candidates live there).
__global__ void mask_collect_k(const float* __restrict__ A, const float* __restrict__ B,
                               float* __restrict__ out, uint32_t* __restrict__ ws,
                               uint32_t* __restrict__ outbuf, int nvec, int n) {
  const int m = blockIdx.y;
  const float4* __restrict__ src = (const float4*)(m == 0 ? A : B);
  float4* __restrict__ dst = (float4*)(out + (size_t)m * (size_t)n);
  uint32_t* W = ws + m * 8;
  uint32_t* cand = outbuf + RBASE + (uint32_t)m * (CCAP * 2u);
  const uint32_t P = W[0];
  int idx0 = blockIdx.x * blockDim.x + threadIdx.x;
  int stride = gridDim.x * blockDim.x;
  for (int i = idx0; i < nvec; i += stride) {
    float4 f = src[i];
    const float v[4] = {f.x, f.y, f.z, f.w};
    float r[4];
#pragma unroll
    for (int c = 0; c < 4; c++) {
      uint32_t u = __float_as_uint(v[c]) & 0x7fffffffu;
      uint32_t p = u >> 15;
      r[c] = (p > P) ? 1.0f : 0.0f;          // p==P resolved by select_fix_k
      if (p == P) {
        uint32_t s = atomicAdd(&W[2], 1u);
        if (s < CCAP) { cand[2u * s] = (uint32_t)i * 4u + (uint32_t)c; cand[2u * s + 1u] = u; }
      }
    }
    if (!(m == 1 && i >= (int)SKIP_F4)) dst[i] = make_float4(r[0], r[1], r[2], r[3]);
  }
}

// Exact select among candidates: 15 remaining bits -> 32768-bin LDS histogram
// gives the EXACT threshold T (16+15 = full 31 bits); the selected bin IS the
// tie set. Then resolve tie cutoff C and scatter-fix the candidate entries.
// NEVER writes words >= RBASE (m=1 entries there are covered by fill_tail_k),
// so the live candidate buffers are read-only for the whole kernel.
__global__ __launch_bounds__(1024, 1) void select_fix_k(uint32_t* __restrict__ ws,
                                                        uint32_t* __restrict__ outbuf,
                                                        float* __restrict__ out, int n) {
  const int m = blockIdx.x;
  uint32_t* W = ws + m * 8;
  const uint32_t* cand = outbuf + RBASE + (uint32_t)m * (CCAP * 2u);
  __shared__ uint32_t h[32768];
  __shared__ uint32_t ps[1024];
  __shared__ uint32_t sT, sTarget, sC;
  __shared__ uint32_t tie_idx[1024];
  __shared__ uint32_t tie_n;
  const int t = threadIdx.x;
  uint32_t nc = W[2]; if (nc > CCAP) nc = CCAP;
  const uint32_t r = W[1];
  const uint32_t P = W[0];
  if (t == 0) { tie_n = 0u; sT = P << 15; sTarget = 0u; sC = 0u; }
  for (int i = t; i < 32768; i += 1024) h[i] = 0u;
  __syncthreads();
  for (uint32_t e = t; e < nc; e += 1024u)
    atomicAdd(&h[cand[2u * e + 1u] & 32767u], 1u);
  __syncthreads();
  uint32_t s = 0u;
  for (int k = 0; k < 32; k++) s += h[t * 32 + k];
  ps[t] = s;
  __syncthreads();
  for (int off = 1; off < 1024; off <<= 1) {
    uint32_t v = (t >= off) ? ps[t - off] : 0u;
    __syncthreads();
    ps[t] += v;
    __syncthreads();
  }
  uint32_t base = (t == 0) ? 0u : ps[t - 1];
  for (int k = 0; k < 32; k++) {
    uint32_t b = (uint32_t)t * 32u + (uint32_t)k;
    uint32_t c = h[b];
    if (r >= base && r < base + c) { sT = (P << 15) | b; sTarget = r - base; }
    base += c;
  }
  __syncthreads();
  const uint32_t T = sT, target = sTarget;
  for (uint32_t e = t; e < nc; e += 1024u) {
    if (cand[2u * e + 1u] == T) {
      uint32_t slot = atomicAdd(&tie_n, 1u);
      if (slot < 1024u) tie_idx[slot] = cand[2u * e];
    }
  }
  __syncthreads();
  uint32_t E2 = tie_n; if (E2 > 1024u) E2 = 1024u;
  for (uint32_t c2 = t; c2 < E2; c2 += 1024u) {
    uint32_t xi = tie_idx[c2];
    uint32_t lt = 0u;
    for (uint32_t k2 = 0; k2 < E2; k2++) lt += (tie_idx[k2] < xi) ? 1u : 0u;
    if (lt == target) sC = xi;               // target-th smallest tie index
  }
  __syncthreads();
  if (t == 0) { W[3] = T; W[4] = sC; }
  const uint32_t C = sC;
  float* dstf = out + (size_t)m * (size_t)n;
  for (uint32_t e = t; e < nc; e += 1024u) {
    uint32_t idx = cand[2u * e];
    if (m == 1 && idx >= SKIP_WORD) continue;   // covered by fill_tail_k; keeps
                                                // candidate buffers read-only
    uint32_t u = cand[2u * e + 1u];
    dstf[idx] = (u > T || (u == T && idx >= C)) ? 1.0f : 0.0f;
  }
}

// Fill the tail region of matrix-1's output (skipped everywhere else because
// candidates lived there) with the exact rule. Runs after select_fix_k.
__global__ void fill_tail_k(const float* __restrict__ B, float* __restrict__ out,
                            const uint32_t* __restrict__ ws, int n) {
  const uint32_t* W = ws + 8;               // matrix 1 control block
  const uint32_t T = W[3], C = W[4];
  const float4* __restrict__ src = (const float4*)B;
  float4* __restrict__ dst = (float4*)(out + (size_t)n);
  uint32_t i = SKIP_F4 + blockIdx.x * blockDim.x + threadIdx.x;
  if (i < (uint32_t)(n / 4)) {
    float4 f = src[i];
    const float v[4] = {f.x, f.y, f.z, f.w};
    float r[4];
#pragma unroll
    for (int c = 0; c < 4; c++) {
      uint32_t u = __float_as_uint(v[c]) & 0x7fffffffu;
      uint32_t idx = i * 4u + (uint32_t)c;
      r[c] = (u > T || (u == T && idx >= C)) ? 1.0f : 0.0f;
    }
    dst[i] = make_float4(r[0], r[1], r[2], r[3]);
  }
}

extern "C" void kernel_launch(void* const* d_in, const int* in_sizes, int n_in,
                              void* d_out, int out_size, void* d_ws, size_t ws_size,
                              hipStream_t stream) {
  const float* A = (const float*)d_in[0];
  const float* B = (const float*)d_in[1];
  float* out = (float*)d_out;
  uint32_t* ws = (uint32_t*)d_ws;
  uint32_t* outbuf = (uint32_t*)d_out;
  const int n = in_sizes[0];                               // 16777216 per matrix
  const int nvec = n / 4;
  const uint32_t j = (uint32_t)((1.0 - 0.1) * (double)n);  // == Python int((1-k)*n)

  init_k<<<(HWORDS + 255) / 256, 256, 0, stream>>>(ws, outbuf);
  hist_k<<<dim3(128, 2), 1024, 0, stream>>>(A, B, outbuf, nvec);
  scan16_k<<<2, 1024, 0, stream>>>(outbuf, ws, j);
  mask_collect_k<<<dim3(2048, 2), 256, 0, stream>>>(A, B, out, ws, outbuf, nvec, n);
  select_fix_k<<<2, 1024, 0, stream>>>(ws, outbuf, out, n);
  fill_tail_k<<<(n / 4 - SKIP_F4 + 255) / 256, 256, 0, stream>>>(B, out, ws, n);
}

// Round 3
// 419.242 us; speedup vs baseline: 2.4599x; 2.4599x over previous
//
#include <hip/hip_runtime.h>
#include <stdint.h>

// ---------------------------------------------------------------------------
// Exact top-k (k=10%) magnitude mask via 16-bit-prefix radix select.
//
// Layout:
//  d_out (128 MiB, 33554432 fp32 words) is scratch until final masks land:
//    words [0, 131072)        : two 65536-bin uint32 histograms (m=0, m=1)
//                               (clobbered later by matrix-0's provisional mask)
//    words [RBASE, 33554432)  : candidate (idx,u) pairs, 65536 cap per matrix
//                               (matrix-1 provisional write SKIPS this tail;
//                                select_fix_k also never writes there;
//                                fill_tail_k writes it exactly at the end)
//  d_ws: 64 uint32 control words. per matrix m at ws+8*m:
//    [0]=P (16-bit prefix of threshold), [1]=rank within prefix bin,
//    [3]=T (exact 31-bit threshold), [4]=C (tie cutoff idx)
//  candidate counters live on their OWN cache lines: ws[32] (m=0), ws[48] (m=1)
//  so the heavily-read P line is never dirtied by atomics.
// ---------------------------------------------------------------------------

#define NBINS       65536u
#define HWORDS      (2u * NBINS)                    // 131072 words of d_out
#define CCAP        65536u                          // expected ~32768/matrix -> 2x headroom
#define TOTAL_WORDS 33554432u                       // d_out words (2 x 16.7M fp32)
#define RWORDS      (2u * CCAP * 2u)                // 262144 words = 1 MiB
#define RBASE       (TOTAL_WORDS - RWORDS)          // 33292288
#define SKIP_WORD   (RBASE - 16777216u)             // 16515072 (local fp32 idx, matrix 1)
#define SKIP_F4     (SKIP_WORD / 4u)                // 4128768 (float4 idx in matrix 1)
#define CNT(m)      (32u + (uint32_t)(m) * 16u)     // per-matrix global counter word
#define LCAP        256u                            // per-block candidate staging cap

__global__ void init_k(uint32_t* __restrict__ ws, uint32_t* __restrict__ outbuf) {
  uint32_t i = blockIdx.x * blockDim.x + threadIdx.x;
  if (i < HWORDS) outbuf[i] = 0u;
  if (i < 64u) ws[i] = 0u;
}

// PASS 1: full scan, 65536-bin histogram of bits 30..15.
// Bins packed 2x16-bit in 128 KiB LDS; per-block max bin count ~512 so no
// 16-bit overflow. Hottest bin ~0.2% of elements -> near-zero LDS atomic
// serialization.
__global__ __launch_bounds__(1024, 1) void hist_k(const float* __restrict__ A,
                                                  const float* __restrict__ B,
                                                  uint32_t* __restrict__ outbuf,
                                                  int nvec) {
  const int m = blockIdx.y;
  const float4* __restrict__ src = (const float4*)(m == 0 ? A : B);
  uint32_t* gh = outbuf + (uint32_t)m * NBINS;
  __shared__ uint32_t h[NBINS / 2];
  for (int i = threadIdx.x; i < (int)(NBINS / 2); i += blockDim.x) h[i] = 0u;
  __syncthreads();
  int idx0 = blockIdx.x * blockDim.x + threadIdx.x;
  int stride = gridDim.x * blockDim.x;
  for (int i = idx0; i < nvec; i += stride) {
    float4 f = src[i];
    const float v[4] = {f.x, f.y, f.z, f.w};
#pragma unroll
    for (int c = 0; c < 4; c++) {
      uint32_t u = __float_as_uint(v[c]) & 0x7fffffffu;
      uint32_t b = u >> 15;
      atomicAdd(&h[b >> 1], 1u << ((b & 1u) * 16u));
    }
  }
  __syncthreads();
  // merge: skip zero words (sparse tail of low binades)
  for (int w = threadIdx.x; w < (int)(NBINS / 2); w += blockDim.x) {
    uint32_t x = h[w];
    uint32_t c0 = x & 0xffffu, c1 = x >> 16;
    if (c0) atomicAdd(&gh[2 * w], c0);
    if (c1) atomicAdd(&gh[2 * w + 1], c1);
  }
}

// Scan the 65536-bin histogram: find bin containing rank j -> P, rank-in-bin.
__global__ __launch_bounds__(1024, 1) void scan16_k(const uint32_t* __restrict__ outbuf,
                                                    uint32_t* __restrict__ ws, uint32_t j) {
  const int m = blockIdx.x;
  const uint32_t* gh = outbuf + (uint32_t)m * NBINS;
  uint32_t* W = ws + m * 8;
  __shared__ uint32_t ps[1024];
  const int t = threadIdx.x;
  uint32_t s = 0u;
  for (int k = 0; k < 64; k++) s += gh[t * 64 + k];
  ps[t] = s;
  __syncthreads();
  for (int off = 1; off < 1024; off <<= 1) {
    uint32_t v = (t >= off) ? ps[t - off] : 0u;
    __syncthreads();
    ps[t] += v;
    __syncthreads();
  }
  uint32_t base = (t == 0) ? 0u : ps[t - 1];
  for (int k = 0; k < 64; k++) {
    uint32_t b = (uint32_t)t * 64u + (uint32_t)k;
    uint32_t c = gh[b];
    if (j >= base && j < base + c) { W[0] = b; W[1] = j - base; }  // one match
    base += c;
  }
}

// PASS 2 (fused with final mask): write provisional mask by 16-bit prefix
// comparison; collect prefix-matching (idx,u) pairs. Candidates are staged in
// LDS (cheap LDS atomics) and flushed with ONE global atomicAdd per block --
// the previous per-element same-address global atomic serialized the whole
// kernel (703 us at 0.9% VALUBusy).
__global__ void mask_collect_k(const float* __restrict__ A, const float* __restrict__ B,
                               float* __restrict__ out, uint32_t* __restrict__ ws,
                               uint32_t* __restrict__ outbuf, int nvec, int n) {
  const int m = blockIdx.y;
  const float4* __restrict__ src = (const float4*)(m == 0 ? A : B);
  float4* __restrict__ dst = (float4*)(out + (size_t)m * (size_t)n);
  const uint32_t P = ws[m * 8];
  uint32_t* cand = outbuf + RBASE + (uint32_t)m * (CCAP * 2u);
  __shared__ uint32_t lbuf[2u * LCAP];
  __shared__ uint32_t ln, lbase;
  if (threadIdx.x == 0) ln = 0u;
  __syncthreads();
  int idx0 = blockIdx.x * blockDim.x + threadIdx.x;
  int stride = gridDim.x * blockDim.x;
  for (int i = idx0; i < nvec; i += stride) {
    float4 f = src[i];
    const float v[4] = {f.x, f.y, f.z, f.w};
    float r[4];
#pragma unroll
    for (int c = 0; c < 4; c++) {
      uint32_t u = __float_as_uint(v[c]) & 0x7fffffffu;
      uint32_t p = u >> 15;
      r[c] = (p > P) ? 1.0f : 0.0f;          // p==P resolved by select_fix_k
      if (p == P) {
        uint32_t s = atomicAdd(&ln, 1u);     // LDS atomic: cheap
        if (s < LCAP) { lbuf[2u * s] = (uint32_t)i * 4u + (uint32_t)c; lbuf[2u * s + 1u] = u; }
      }
    }
    if (!(m == 1 && i >= (int)SKIP_F4)) dst[i] = make_float4(r[0], r[1], r[2], r[3]);
  }
  __syncthreads();
  uint32_t c = ln; if (c > LCAP) c = LCAP;
  if (threadIdx.x == 0 && c) lbase = atomicAdd(&ws[CNT(m)], c);   // ONE global atomic/block
  __syncthreads();
  for (uint32_t t = threadIdx.x; t < c; t += blockDim.x) {
    uint32_t g = lbase + t;
    if (g < CCAP) { cand[2u * g] = lbuf[2u * t]; cand[2u * g + 1u] = lbuf[2u * t + 1u]; }
  }
}

// Exact select among candidates: 15 remaining bits -> 32768-bin LDS histogram
// gives the EXACT threshold T (16+15 = full 31 bits); the selected bin IS the
// tie set. Then resolve tie cutoff C and scatter-fix the candidate entries.
// NEVER writes words >= RBASE (m=1 entries there are covered by fill_tail_k).
__global__ __launch_bounds__(1024, 1) void select_fix_k(uint32_t* __restrict__ ws,
                                                        uint32_t* __restrict__ outbuf,
                                                        float* __restrict__ out, int n) {
  const int m = blockIdx.x;
  uint32_t* W = ws + m * 8;
  const uint32_t* cand = outbuf + RBASE + (uint32_t)m * (CCAP * 2u);
  __shared__ uint32_t h[32768];
  __shared__ uint32_t ps[1024];
  __shared__ uint32_t sT, sTarget, sC;
  __shared__ uint32_t tie_idx[1024];
  __shared__ uint32_t tie_n;
  const int t = threadIdx.x;
  uint32_t nc = ws[CNT(m)]; if (nc > CCAP) nc = CCAP;
  const uint32_t r = W[1];
  const uint32_t P = W[0];
  if (t == 0) { tie_n = 0u; sT = P << 15; sTarget = 0u; sC = 0u; }
  for (int i = t; i < 32768; i += 1024) h[i] = 0u;
  __syncthreads();
  for (uint32_t e = t; e < nc; e += 1024u)
    atomicAdd(&h[cand[2u * e + 1u] & 32767u], 1u);
  __syncthreads();
  uint32_t s = 0u;
  for (int k = 0; k < 32; k++) s += h[t * 32 + k];
  ps[t] = s;
  __syncthreads();
  for (int off = 1; off < 1024; off <<= 1) {
    uint32_t v = (t >= off) ? ps[t - off] : 0u;
    __syncthreads();
    ps[t] += v;
    __syncthreads();
  }
  uint32_t base = (t == 0) ? 0u : ps[t - 1];
  for (int k = 0; k < 32; k++) {
    uint32_t b = (uint32_t)t * 32u + (uint32_t)k;
    uint32_t c = h[b];
    if (r >= base && r < base + c) { sT = (P << 15) | b; sTarget = r - base; }
    base += c;
  }
  __syncthreads();
  const uint32_t T = sT, target = sTarget;
  for (uint32_t e = t; e < nc; e += 1024u) {
    if (cand[2u * e + 1u] == T) {
      uint32_t slot = atomicAdd(&tie_n, 1u);
      if (slot < 1024u) tie_idx[slot] = cand[2u * e];
    }
  }
  __syncthreads();
  uint32_t E2 = tie_n; if (E2 > 1024u) E2 = 1024u;
  for (uint32_t c2 = t; c2 < E2; c2 += 1024u) {
    uint32_t xi = tie_idx[c2];
    uint32_t lt = 0u;
    for (uint32_t k2 = 0; k2 < E2; k2++) lt += (tie_idx[k2] < xi) ? 1u : 0u;
    if (lt == target) sC = xi;               // target-th smallest tie index
  }
  __syncthreads();
  if (t == 0) { W[3] = T; W[4] = sC; }
  const uint32_t C = sC;
  float* dstf = out + (size_t)m * (size_t)n;
  for (uint32_t e = t; e < nc; e += 1024u) {
    uint32_t idx = cand[2u * e];
    if (m == 1 && idx >= SKIP_WORD) continue;   // covered by fill_tail_k; keeps
                                                // candidate buffers read-only
    uint32_t u = cand[2u * e + 1u];
    dstf[idx] = (u > T || (u == T && idx >= C)) ? 1.0f : 0.0f;
  }
}

// Fill the tail region of matrix-1's output (skipped everywhere else because
// candidates lived there) with the exact rule. Runs after select_fix_k.
__global__ void fill_tail_k(const float* __restrict__ B, float* __restrict__ out,
                            const uint32_t* __restrict__ ws, int n) {
  const uint32_t* W = ws + 8;               // matrix 1 control block
  const uint32_t T = W[3], C = W[4];
  const float4* __restrict__ src = (const float4*)B;
  float4* __restrict__ dst = (float4*)(out + (size_t)n);
  uint32_t i = SKIP_F4 + blockIdx.x * blockDim.x + threadIdx.x;
  if (i < (uint32_t)(n / 4)) {
    float4 f = src[i];
    const float v[4] = {f.x, f.y, f.z, f.w};
    float r[4];
#pragma unroll
    for (int c = 0; c < 4; c++) {
      uint32_t u = __float_as_uint(v[c]) & 0x7fffffffu;
      uint32_t idx = i * 4u + (uint32_t)c;
      r[c] = (u > T || (u == T && idx >= C)) ? 1.0f : 0.0f;
    }
    dst[i] = make_float4(r[0], r[1], r[2], r[3]);
  }
}

extern "C" void kernel_launch(void* const* d_in, const int* in_sizes, int n_in,
                              void* d_out, int out_size, void* d_ws, size_t ws_size,
                              hipStream_t stream) {
  const float* A = (const float*)d_in[0];
  const float* B = (const float*)d_in[1];
  float* out = (float*)d_out;
  uint32_t* ws = (uint32_t*)d_ws;
  uint32_t* outbuf = (uint32_t*)d_out;
  const int n = in_sizes[0];                               // 16777216 per matrix
  const int nvec = n / 4;
  const uint32_t j = (uint32_t)((1.0 - 0.1) * (double)n);  // == Python int((1-k)*n)

  init_k<<<(HWORDS + 255) / 256, 256, 0, stream>>>(ws, outbuf);
  hist_k<<<dim3(128, 2), 1024, 0, stream>>>(A, B, outbuf, nvec);
  scan16_k<<<2, 1024, 0, stream>>>(outbuf, ws, j);
  mask_collect_k<<<dim3(4096, 2), 256, 0, stream>>>(A, B, out, ws, outbuf, nvec, n);
  select_fix_k<<<2, 1024, 0, stream>>>(ws, outbuf, out, n);
  fill_tail_k<<<(n / 4 - SKIP_F4 + 255) / 256, 256, 0, stream>>>(B, out, ws, n);
}

// Round 5
// 413.427 us; speedup vs baseline: 2.4945x; 1.0141x over previous
//
#include <hip/hip_runtime.h>
#include <stdint.h>

// ---------------------------------------------------------------------------
// Exact top-k (k=10%) magnitude mask via 16-bit-prefix radix select.
//
// Layout:
//  d_out (128 MiB, 33554432 fp32 words) is scratch until final masks land:
//    words [0, 131072)        : two 65536-bin uint32 histograms (m=0, m=1)
//    words [RBASE, 33554432)  : candidate (idx,u) pairs, 65536 cap per matrix
//                               (matrix-1 provisional write SKIPS this tail;
//                                select_fix_k never writes there;
//                                fill_tail_k writes it exactly at the end)
//  d_ws: 64 uint32 control words. per matrix m at ws+8*m:
//    [0]=P (16-bit prefix), [1]=rank within prefix bin,
//    [3]=T (exact 31-bit threshold), [4]=C (tie cutoff idx)
//  candidate counters on own cache lines: ws[32] (m=0), ws[48] (m=1).
// ---------------------------------------------------------------------------

#define NBINS       65536u
#define HWORDS      (2u * NBINS)
#define CCAP        65536u
#define TOTAL_WORDS 33554432u
#define RWORDS      (2u * CCAP * 2u)                // 262144 words = 1 MiB
#define RBASE       (TOTAL_WORDS - RWORDS)          // 33292288
#define SKIP_WORD   (RBASE - 16777216u)             // 16515072
#define SKIP_F4     (SKIP_WORD / 4u)                // 4128768
#define CNT(m)      (32u + (uint32_t)(m) * 16u)
#define LCAP        256u

typedef float floatx4 __attribute__((ext_vector_type(4)));  // native vector for
// __builtin_nontemporal_store (HIP's float4 is a struct and is rejected).

__device__ __forceinline__ void nt_store4(float4* p, float a, float b, float c, float d) {
  floatx4 v = {a, b, c, d};
  __builtin_nontemporal_store(v, reinterpret_cast<floatx4*>(p));
}

__global__ void init_k(uint32_t* __restrict__ ws, uint32_t* __restrict__ outbuf) {
  uint32_t i = blockIdx.x * blockDim.x + threadIdx.x;
  if (i < HWORDS) outbuf[i] = 0u;
  if (i < 64u) ws[i] = 0u;
}

// PASS 1: full scan, 65536-bin histogram of bits 30..15.
// Bins packed 2x16-bit in 128 KiB LDS; per-block max bin count ~256. Inputs
// allocate in L3 here and are re-read (L3-hit) by mask_collect_k.
__global__ __launch_bounds__(1024, 1) void hist_k(const float* __restrict__ A,
                                                  const float* __restrict__ B,
                                                  uint32_t* __restrict__ outbuf,
                                                  int nvec) {
  const int m = blockIdx.y;
  const float4* __restrict__ src = (const float4*)(m == 0 ? A : B);
  uint32_t* gh = outbuf + (uint32_t)m * NBINS;
  __shared__ uint32_t h[NBINS / 2];
  for (int i = threadIdx.x; i < (int)(NBINS / 2); i += blockDim.x) h[i] = 0u;
  __syncthreads();
  int idx0 = blockIdx.x * blockDim.x + threadIdx.x;
  int stride = gridDim.x * blockDim.x;
  for (int i = idx0; i < nvec; i += stride) {
    float4 f = src[i];
    const float v[4] = {f.x, f.y, f.z, f.w};
#pragma unroll
    for (int c = 0; c < 4; c++) {
      uint32_t u = __float_as_uint(v[c]) & 0x7fffffffu;
      uint32_t b = u >> 15;
      atomicAdd(&h[b >> 1], 1u << ((b & 1u) * 16u));
    }
  }
  __syncthreads();
  for (int w = threadIdx.x; w < (int)(NBINS / 2); w += blockDim.x) {
    uint32_t x = h[w];
    uint32_t c0 = x & 0xffffu, c1 = x >> 16;
    if (c0) atomicAdd(&gh[2 * w], c0);
    if (c1) atomicAdd(&gh[2 * w + 1], c1);
  }
}

// Scan the 65536-bin histogram: find bin containing rank j -> P, rank-in-bin.
// Coalesced: wave w, iter k reads 64 CONSECUTIVE bins (one 256B transaction),
// shfl-reduces to the chunk sum.
__global__ __launch_bounds__(1024, 1) void scan16_k(const uint32_t* __restrict__ outbuf,
                                                    uint32_t* __restrict__ ws, uint32_t j) {
  const int m = blockIdx.x;
  const uint32_t* gh = outbuf + (uint32_t)m * NBINS;
  uint32_t* W = ws + m * 8;
  __shared__ uint32_t csum[1024];
  __shared__ uint32_t ps[1024];
  __shared__ uint32_t sChunk, sRank;
  __shared__ uint32_t bins[64];
  const int t = threadIdx.x;
  const int w = t >> 6, l = t & 63;
  // chunk c = w*64+k covers bins [c*64, c*64+64)
  for (int k = 0; k < 64; k++) {
    uint32_t v = gh[(w << 12) + (k << 6) + l];
#pragma unroll
    for (int off = 32; off; off >>= 1) v += __shfl_xor(v, off, 64);
    if (l == 0) csum[(w << 6) + k] = v;
  }
  __syncthreads();
  ps[t] = csum[t];
  __syncthreads();
  for (int off = 1; off < 1024; off <<= 1) {
    uint32_t v = (t >= off) ? ps[t - off] : 0u;
    __syncthreads();
    ps[t] += v;
    __syncthreads();
  }
  uint32_t base = (t == 0) ? 0u : ps[t - 1];
  if (j >= base && j < base + csum[t]) { sChunk = (uint32_t)t; sRank = j - base; }
  __syncthreads();
  const uint32_t chunk = sChunk, rk = sRank;
  if (t < 64) bins[t] = gh[chunk * 64u + (uint32_t)t];
  __syncthreads();
  if (t < 64) {
    uint32_t lt = 0u;
    for (int k2 = 0; k2 < t; k2++) lt += bins[k2];
    if (rk >= lt && rk < lt + bins[t]) { W[0] = chunk * 64u + (uint32_t)t; W[1] = rk - lt; }
  }
}

// PASS 2 (fused with final mask): provisional mask by 16-bit prefix compare;
// candidates staged in LDS, flushed with ONE global atomicAdd per block.
// Mask stores are NON-TEMPORAL: without this, 128 MiB of mask writes allocate
// in L3 and evict the 128 MiB of inputs (L3=256MiB, exact thrash) -- round-3
// counters showed FETCH=65MB (half the inputs re-fetched from HBM).
__global__ void mask_collect_k(const float* __restrict__ A, const float* __restrict__ B,
                               float* __restrict__ out, uint32_t* __restrict__ ws,
                               uint32_t* __restrict__ outbuf, int nvec, int n) {
  const int m = blockIdx.y;
  const float4* __restrict__ src = (const float4*)(m == 0 ? A : B);
  float4* __restrict__ dst = (float4*)(out + (size_t)m * (size_t)n);
  const uint32_t P = ws[m * 8];
  uint32_t* cand = outbuf + RBASE + (uint32_t)m * (CCAP * 2u);
  __shared__ uint32_t lbuf[2u * LCAP];
  __shared__ uint32_t ln, lbase;
  if (threadIdx.x == 0) ln = 0u;
  __syncthreads();
  const int i0 = blockIdx.x * blockDim.x + threadIdx.x;
  const int S = gridDim.x * blockDim.x;
  // batch all 4 loads up front for MLP (grid sized so nvec == 4*S)
  float4 f[4];
#pragma unroll
  for (int q = 0; q < 4; q++) {
    int i = i0 + q * S;
    if (i < nvec) f[q] = src[i];
  }
#pragma unroll
  for (int q = 0; q < 4; q++) {
    int i = i0 + q * S;
    if (i >= nvec) break;
    const float v[4] = {f[q].x, f[q].y, f[q].z, f[q].w};
    float r[4];
#pragma unroll
    for (int c = 0; c < 4; c++) {
      uint32_t u = __float_as_uint(v[c]) & 0x7fffffffu;
      uint32_t p = u >> 15;
      r[c] = (p > P) ? 1.0f : 0.0f;          // p==P resolved by select_fix_k
      if (p == P) {
        uint32_t s = atomicAdd(&ln, 1u);     // LDS atomic: cheap
        if (s < LCAP) { lbuf[2u * s] = (uint32_t)i * 4u + (uint32_t)c; lbuf[2u * s + 1u] = u; }
      }
    }
    if (!(m == 1 && i >= (int)SKIP_F4))
      nt_store4(&dst[i], r[0], r[1], r[2], r[3]);
  }
  __syncthreads();
  uint32_t c = ln; if (c > LCAP) c = LCAP;
  if (threadIdx.x == 0 && c) lbase = atomicAdd(&ws[CNT(m)], c);   // ONE global atomic/block
  __syncthreads();
  for (uint32_t t = threadIdx.x; t < c; t += blockDim.x) {
    uint32_t g = lbase + t;
    if (g < CCAP) { cand[2u * g] = lbuf[2u * t]; cand[2u * g + 1u] = lbuf[2u * t + 1u]; }
  }
}

// Exact select among candidates: 15 remaining bits -> 32768-bin LDS histogram
// gives the EXACT threshold T; selected bin IS the tie set. Resolve tie cutoff
// C, scatter-fix candidate entries. Never writes words >= RBASE.
__global__ __launch_bounds__(1024, 1) void select_fix_k(uint32_t* __restrict__ ws,
                                                        uint32_t* __restrict__ outbuf,
                                                        float* __restrict__ out, int n) {
  const int m = blockIdx.x;
  uint32_t* W = ws + m * 8;
  const uint32_t* cand = outbuf + RBASE + (uint32_t)m * (CCAP * 2u);
  __shared__ uint32_t h[32768];
  __shared__ uint32_t ps[1024];
  __shared__ uint32_t sT, sTarget, sC;
  __shared__ uint32_t tie_idx[1024];
  __shared__ uint32_t tie_n;
  const int t = threadIdx.x;
  uint32_t nc = ws[CNT(m)]; if (nc > CCAP) nc = CCAP;
  const uint32_t r = W[1];
  const uint32_t P = W[0];
  if (t == 0) { tie_n = 0u; sT = P << 15; sTarget = 0u; sC = 0u; }
  for (int i = t; i < 32768; i += 1024) h[i] = 0u;
  __syncthreads();
  for (uint32_t e = t; e < nc; e += 1024u)
    atomicAdd(&h[cand[2u * e + 1u] & 32767u], 1u);
  __syncthreads();
  uint32_t s = 0u;
  for (int k = 0; k < 32; k++) s += h[t * 32 + k];
  ps[t] = s;
  __syncthreads();
  for (int off = 1; off < 1024; off <<= 1) {
    uint32_t v = (t >= off) ? ps[t - off] : 0u;
    __syncthreads();
    ps[t] += v;
    __syncthreads();
  }
  uint32_t base = (t == 0) ? 0u : ps[t - 1];
  for (int k = 0; k < 32; k++) {
    uint32_t b = (uint32_t)t * 32u + (uint32_t)k;
    uint32_t c = h[b];
    if (r >= base && r < base + c) { sT = (P << 15) | b; sTarget = r - base; }
    base += c;
  }
  __syncthreads();
  const uint32_t T = sT, target = sTarget;
  for (uint32_t e = t; e < nc; e += 1024u) {
    if (cand[2u * e + 1u] == T) {
      uint32_t slot = atomicAdd(&tie_n, 1u);
      if (slot < 1024u) tie_idx[slot] = cand[2u * e];
    }
  }
  __syncthreads();
  uint32_t E2 = tie_n; if (E2 > 1024u) E2 = 1024u;
  for (uint32_t c2 = t; c2 < E2; c2 += 1024u) {
    uint32_t xi = tie_idx[c2];
    uint32_t lt = 0u;
    for (uint32_t k2 = 0; k2 < E2; k2++) lt += (tie_idx[k2] < xi) ? 1u : 0u;
    if (lt == target) sC = xi;               // target-th smallest tie index
  }
  __syncthreads();
  if (t == 0) { W[3] = T; W[4] = sC; }
  const uint32_t C = sC;
  float* dstf = out + (size_t)m * (size_t)n;
  for (uint32_t e = t; e < nc; e += 1024u) {
    uint32_t idx = cand[2u * e];
    if (m == 1 && idx >= SKIP_WORD) continue;   // covered by fill_tail_k
    uint32_t u = cand[2u * e + 1u];
    dstf[idx] = (u > T || (u == T && idx >= C)) ? 1.0f : 0.0f;
  }
}

// Fill the tail region of matrix-1's output with the exact rule.
__global__ void fill_tail_k(const float* __restrict__ B, float* __restrict__ out,
                            const uint32_t* __restrict__ ws, int n) {
  const uint32_t* W = ws + 8;
  const uint32_t T = W[3], C = W[4];
  const float4* __restrict__ src = (const float4*)B;
  float4* __restrict__ dst = (float4*)(out + (size_t)n);
  uint32_t i = SKIP_F4 + blockIdx.x * blockDim.x + threadIdx.x;
  if (i < (uint32_t)(n / 4)) {
    float4 f = src[i];
    const float v[4] = {f.x, f.y, f.z, f.w};
    float r[4];
#pragma unroll
    for (int c = 0; c < 4; c++) {
      uint32_t u = __float_as_uint(v[c]) & 0x7fffffffu;
      uint32_t idx = i * 4u + (uint32_t)c;
      r[c] = (u > T || (u == T && idx >= C)) ? 1.0f : 0.0f;
    }
    nt_store4(&dst[i], r[0], r[1], r[2], r[3]);
  }
}

extern "C" void kernel_launch(void* const* d_in, const int* in_sizes, int n_in,
                              void* d_out, int out_size, void* d_ws, size_t ws_size,
                              hipStream_t stream) {
  const float* A = (const float*)d_in[0];
  const float* B = (const float*)d_in[1];
  float* out = (float*)d_out;
  uint32_t* ws = (uint32_t*)d_ws;
  uint32_t* outbuf = (uint32_t*)d_out;
  const int n = in_sizes[0];                               // 16777216 per matrix
  const int nvec = n / 4;
  const uint32_t j = (uint32_t)((1.0 - 0.1) * (double)n);  // == Python int((1-k)*n)

  init_k<<<(HWORDS + 255) / 256, 256, 0, stream>>>(ws, outbuf);
  hist_k<<<dim3(128, 2), 1024, 0, stream>>>(A, B, outbuf, nvec);
  scan16_k<<<2, 1024, 0, stream>>>(outbuf, ws, j);
  mask_collect_k<<<dim3(4096, 2), 256, 0, stream>>>(A, B, out, ws, outbuf, nvec, n);
  select_fix_k<<<2, 1024, 0, stream>>>(ws, outbuf, out, n);
  fill_tail_k<<<(n / 4 - SKIP_F4 + 255) / 256, 256, 0, stream>>>(B, out, ws, n);
}